// Round 1
// 66.222 us; speedup vs baseline: 1.0683x; 1.0683x over previous
//
#include <hip/hip_runtime.h>

#define BN 512
#define DIM 128
#define TMARGIN 0.3f
#define NT 512
#define NW 8      // waves per block
#define NBLK 256  // 2 anchors per block
#define BIGF 1e30f

#define FMA4(ACC, U, V)                                                \
    ACC.x += U.x * V.x; ACC.y += U.y * V.y;                            \
    ACC.z += U.z * V.z; ACC.w += U.w * V.w;

__device__ __forceinline__ float hsum4(float4 v) {
    return (v.x + v.y) + (v.z + v.w);
}

// ---------------------------------------------------------------------------
// 256 blocks x 512 threads (1 block/CU, 8 waves). Block b handles anchors
// b and b+256.
//
// vs previous version:
//  * Anchor vectors live in REGISTERS (each thread only needs its kl-slice:
//    8 float4 per anchor = 64 VGPR) -> removes 64 ds_read_b128/thread from
//    Phase A's inner loop.  VGPR budget is free: 512-thread block = 2
//    waves/SIMD, so up to 256 VGPRs cost nothing.
//  * Negative mask folded into the distance row at write time:
//    drowX[r] = (lab[r]==liX) ? 1e30 : dist.  Phase B loops touch ONLY
//    drow[] (no label LDS reads, no compares); 1e30 auto-fails dan<dap+M
//    and is the identity for the min-neg reduction. has_neg == (min<1e29).
//  * Positive list built inline in Phase A by the writer lane, storing the
//    positive DISTANCE directly (pd[]) -> the separate list-build pass and
//    its second label scan are gone.
//  * Finalize is a single wave, no LDS, no barriers.
// ---------------------------------------------------------------------------
__global__ __launch_bounds__(NT, 1) void triplet_fused_kernel(
        const float* __restrict__ emb,
        const int* __restrict__ labels,
        float* __restrict__ psum,    // [NBLK]
        float* __restrict__ pcnt) {  // [NBLK]
    const int ia   = blockIdx.x;         // anchor A
    const int ib   = blockIdx.x + NBLK;  // anchor B
    const int tid  = threadIdx.x;
    const int lane = tid & 63;
    const int wave = tid >> 6;
    const int rl   = lane >> 2;   // row-in-group 0..15
    const int kl   = lane & 3;    // k-lane 0..3

    __shared__ float drowA[BN], drowB[BN];   // negatives-only distance rows
    __shared__ float pdA[BN], pdB[BN];       // positive distances (compact)
    __shared__ int   nposA, nposB;
    __shared__ float wsum[NW];
    __shared__ int   wcnt[NW];

    const float4* emb4 = (const float4*)emb;
    const int liA = labels[ia];
    const int liB = labels[ib];

    // --- anchor fragments in registers (kl-slice only) --------------------
    float4 ra[8], rb[8];
#pragma unroll
    for (int q = 0; q < 8; ++q) {
        ra[q] = emb4[(size_t)ia * 32 + kl + 4 * q];
        rb[q] = emb4[(size_t)ib * 32 + kl + 4 * q];
    }
    // squared norms: per-thread partial over the kl-slice, then 4-lane sum
    float4 sa = {0,0,0,0}, sb = {0,0,0,0};
#pragma unroll
    for (int q = 0; q < 8; ++q) { FMA4(sa, ra[q], ra[q]); FMA4(sb, rb[q], rb[q]); }
    float sqA = hsum4(sa), sqB = hsum4(sb);
    sqA += __shfl_xor(sqA, 1); sqA += __shfl_xor(sqA, 2);
    sqB += __shfl_xor(sqB, 1); sqB += __shfl_xor(sqB, 2);

    if (tid == 0) { nposA = 0; nposB = 0; }
    __syncthreads();

    // ---------------- Phase A: both dist rows, one pass over emb ----------
    // 8 waves x 16 rows/iter; 4 lanes per row, 64 B contiguous per group.
#pragma unroll
    for (int c = 0; c < 4; ++c) {
        const int r = c * 128 + wave * 16 + rl;
        float4 da = {0,0,0,0}, db = {0,0,0,0}, qq = {0,0,0,0};
#pragma unroll
        for (int q = 0; q < 8; ++q) {
            const float4 v = emb4[(size_t)r * 32 + kl + 4 * q];
            FMA4(da, ra[q], v);
            FMA4(db, rb[q], v);
            FMA4(qq, v, v);
        }
        float dotA = hsum4(da), dotB = hsum4(db), sqj = hsum4(qq);
        dotA += __shfl_down(dotA, 1); dotA += __shfl_down(dotA, 2);
        dotB += __shfl_down(dotB, 1); dotB += __shfl_down(dotB, 2);
        sqj  += __shfl_down(sqj, 1);  sqj  += __shfl_down(sqj, 2);
        if (kl == 0) {
            const int   lr = labels[r];
            const float dA = sqrtf(fmaxf(sqA + sqj - 2.f * dotA, 1e-12f));
            const float dB = sqrtf(fmaxf(sqB + sqj - 2.f * dotB, 1e-12f));
            const bool  eqA = (lr == liA), eqB = (lr == liB);
            drowA[r] = eqA ? BIGF : dA;     // self has eqA -> excluded too
            drowB[r] = eqB ? BIGF : dB;
            if (eqA && r != ia) { int p = atomicAdd(&nposA, 1); pdA[p] = dA; }
            if (eqB && r != ib) { int p = atomicAdd(&nposB, 1); pdB[p] = dB; }
        }
    }
    __syncthreads();

    // ---------------- Phase B: waves 0-3 anchor A, 4-7 anchor B -----------
    const int grp  = wave >> 2;             // 0: A, 1: B
    const int wsub = wave & 3;
    const float* drow = grp ? drowB : drowA;
    const float* pd   = grp ? pdB   : pdA;
    const int    npos = grp ? nposB : nposA;

    // min over negatives (BIGF is identity); has_neg == (mn < 1e29)
    float mn = BIGF;
#pragma unroll
    for (int kk = 0; kk < BN / 64; ++kk)
        mn = fminf(mn, drow[lane + 64 * kk]);
#pragma unroll
    for (int off = 32; off; off >>= 1)
        mn = fminf(mn, __shfl_xor(mn, off));

    float lsum = 0.f;
    int   lcnt = 0;
    if (mn < 1e29f) {
        for (int p = wsub; p < npos; p += 4) {
            const float dap = pd[p];
            const float hi  = dap + TMARGIN;
            float smax = -BIGF;
#pragma unroll
            for (int kk = 0; kk < BN / 64; ++kk) {
                const float dan = drow[lane + 64 * kk];
                if (dan > dap && dan < hi) smax = fmaxf(smax, dan);
            }
#pragma unroll
            for (int off = 32; off; off >>= 1)
                smax = fmaxf(smax, __shfl_xor(smax, off));
            const float dneg = (smax > -1e29f) ? smax : mn;
            lsum += fmaxf(dap - dneg + TMARGIN, 0.f);
            lcnt += 1;
        }
    }
    if (lane == 0) { wsum[wave] = lsum; wcnt[wave] = lcnt; }
    __syncthreads();

    // one combined partial per block; plain stores (kernel-end flush)
    if (tid == 0) {
        float s = 0.f;
        int   c = 0;
#pragma unroll
        for (int w = 0; w < NW; ++w) { s += wsum[w]; c += wcnt[w]; }
        psum[blockIdx.x] = s;
        pcnt[blockIdx.x] = (float)c;
    }
}

// ---------------------------------------------------------------------------
// Finalize: one wave reduces the 256 partial slots. No LDS, no barriers.
// ---------------------------------------------------------------------------
__global__ __launch_bounds__(64) void finalize_kernel(
        const float* __restrict__ psum,
        const float* __restrict__ pcnt,
        float* __restrict__ out) {
    const int lane = threadIdx.x;
    float s = 0.f, c = 0.f;
#pragma unroll
    for (int i = 0; i < 4; ++i) {
        s += psum[lane + 64 * i];
        c += pcnt[lane + 64 * i];
    }
#pragma unroll
    for (int off = 32; off; off >>= 1) {
        s += __shfl_xor(s, off);
        c += __shfl_xor(c, off);
    }
    if (lane == 0)
        out[0] = (c > 0.f) ? (s / fmaxf(c, 1.f)) : 0.f;
}

extern "C" void kernel_launch(void* const* d_in, const int* in_sizes, int n_in,
                              void* d_out, int out_size, void* d_ws, size_t ws_size,
                              hipStream_t stream) {
    const float* emb    = (const float*)d_in[0];
    const int*   labels = (const int*)d_in[1];
    float*       out    = (float*)d_out;
    float*       psum   = (float*)d_ws;        // [256]
    float*       pcnt   = psum + NBLK;         // [256]

    triplet_fused_kernel<<<NBLK, NT, 0, stream>>>(emb, labels, psum, pcnt);
    finalize_kernel<<<1, 64, 0, stream>>>(psum, pcnt, out);
}